// Round 3
// baseline (446.873 us; speedup 1.0000x reference)
//
#include <hip/hip_runtime.h>
#include <hip/hip_bf16.h>
#include <math.h>

// Problem constants
#define NN   16
#define CI   64
#define HH   224
#define WW   224
#define CO   128
#define OHH  222
#define OWW  222

// ws holds ONLY prep_w's B fragments (144 KB) -> tiny poison cost.
#define WS_NEED (36*4*64*16)   // 147456

typedef short  short8  __attribute__((ext_vector_type(8)));
typedef float  f32x16  __attribute__((ext_vector_type(16)));
typedef float  f32x4   __attribute__((ext_vector_type(4)));

__device__ static inline unsigned f2bf_pk(float a, float b) {
  __hip_bfloat162 h = __float22bfloat162_rn(make_float2(a, b));  // v_cvt_pk_bf16_f32
  return *reinterpret_cast<unsigned*>(&h);
}

// ---------------------------------------------------------------------------
// prep_w: weights [Co][Ci][3][3] fp32 -> B fragments in mfma lane order.
// frag (s, ctg): s = tap*4+cic (tap=kh*3+kw), ctg 0..3; element ((s*4+ctg)*64+lane).
// B[k][n]: n = lane&31 (co within 32-tile), k = (lane>>5)*8 + j.  (UNCHANGED)
// ---------------------------------------------------------------------------
__global__ __launch_bounds__(256) void prep_w_kernel(const float* __restrict__ wt,
                                                     unsigned char* __restrict__ ws) {
  int t    = blockIdx.x * 256 + threadIdx.x;       // 0..9215
  int lane = t & 63;
  int f    = t >> 6;                               // 0..143
  int s    = f >> 2;
  int ct   = f & 3;
  int tap  = s >> 2;
  int cic  = s & 3;
  int kh   = tap / 3, kw = tap % 3;
  int co   = ct * 32 + (lane & 31);
  int k0   = cic * 16 + (lane >> 5) * 8;
  unsigned pk[4];
#pragma unroll
  for (int j = 0; j < 4; ++j) {
    int ci0 = k0 + 2 * j;
    float a = wt[(size_t)co * 576 + (ci0    ) * 9 + kh * 3 + kw];
    float b = wt[(size_t)co * 576 + (ci0 + 1) * 9 + kh * 3 + kw];
    pk[j] = f2bf_pk(a, b);
  }
  ((uint4*)ws)[t] = make_uint4(pk[0], pk[1], pk[2], pk[3]);
}

// ---------------------------------------------------------------------------
// conv v6: restore per-wave ILP (v3's MFMA:load ratio) at v5's occupancy.
// Block 512 thr / 8 waves covers 8 oh x 32 ow x 128 co.
// Wave (mg = wv>>1 -> oh rows 2mg,2mg+1; ng = wv&1 = co half):
// acc[2][2] f32x16 = 64 VGPR; per K-step 4 MFMA : 2 A ds_read + 2 B loads
// (v5 was 2:3 -> latency-bound at MfmaUtil 21%). B L2 traffic halves.
// Steady state: acc 64 + aa 16 + bb 24 + P 8 + temps ~= 120 < 128 (no spill;
// v4's 256-thr variant needed 128+temps -> spilled 150 MB).
// LDS 10*34*128 = 43520 B; 2 blocks/CU = 16 waves (50% occ).
// ---------------------------------------------------------------------------
__global__ __launch_bounds__(512, 4) void conv_min_kernel(
    const float* __restrict__ x, const float* __restrict__ bias,
    const unsigned char* __restrict__ ws, float* __restrict__ out) {
  __shared__ __align__(16) unsigned char smem[10 * 34 * 128];  // 43520 B

  int bid = blockIdx.x;
  // XCD-aware bijective swizzle: grid = 3136 = 8 * 392. Vertical neighbors
  // (bid +/- 7, sharing 2 input rows) land in the same XCD chunk.
  bid = (bid & 7) * (NN * 28 * 7 / 8) + (bid >> 3);

  int owt  = bid % 7;
  int rest = bid / 7;
  int oht  = rest % 28;
  int n    = rest / 28;
  int ow0  = (owt < 6) ? owt * 32 : 190;   // last ow tile overlaps (same values)
  int oh0  = oht * 8;                      // oh 222/223 masked at store

  int tid   = threadIdx.x;
  int wv    = tid >> 6;    // 0..7
  int lane  = tid & 63;
  int mg    = wv >> 1;     // oh row-pair 0..3
  int ng    = wv & 1;      // co half
  int mrow  = lane & 31;
  int khalf = lane >> 5;

  // ---- B prologue (issue before staging so loads overlap) ----
  const short8* wf = (const short8*)ws;
  int bbase = ng * 128 + lane;
  short8 bb[3][2];
#pragma unroll
  for (int ct = 0; ct < 2; ++ct) bb[0][ct] = wf[0 * 256 + ct * 64 + bbase];
#pragma unroll
  for (int ct = 0; ct < 2; ++ct) bb[1][ct] = wf[1 * 256 + ct * 64 + bbase];

  // ---- in-kernel A staging: 10 rows x 34 cols x 64 ci bf16, rotated slots ----
  // slot(row,col): chunk cc (ci 8cc..8cc+7) at byte ((cc+col)&7)*16, word pp&3.
  // 512 threads: each thread does ONE (col-pair, ci-pair) per row.
  {
    int colm = (tid & 15) * 2;     // main cols 0..31 (pairs)
    int q    = tid >> 4;           // ci-pair 0..31
    const float* xb = x + (size_t)n * 64 * 50176;
#pragma unroll 1
    for (int r = 0; r < 10; ++r) {
      int rg = oh0 + r; if (rg > 223) rg = 223;
      const float* xr = xb + (size_t)rg * 224;
      {
        int ci = q * 2;
        const float* s0 = xr + (size_t)ci * 50176 + ow0 + colm;
        float2 a2 = *(const float2*)s0;
        float2 b2 = *(const float2*)(s0 + 50176);
        unsigned u0 = f2bf_pk(a2.x, b2.x);
        unsigned u1 = f2bf_pk(a2.y, b2.y);
        int cc = q >> 2, jw = (q & 3) * 4;
        *(unsigned*)(smem + (r * 34 + colm    ) * 128 + (((cc + colm    ) & 7) << 4) + jw) = u0;
        *(unsigned*)(smem + (r * 34 + colm + 1) * 128 + (((cc + colm + 1) & 7) << 4) + jw) = u1;
      }
      if (tid < 64) {   // halo cols 32,33 (ow0+33 <= 223: never OOB)
        int cole = 32 + (tid & 1);
        int ppe  = tid >> 1;       // 0..31
        const float* s0 = xr + (size_t)(ppe * 2) * 50176 + ow0 + cole;
        float a = s0[0], b = s0[50176];
        *(unsigned*)(smem + (r * 34 + cole) * 128 + ((((ppe >> 2) + cole) & 7) << 4) + (ppe & 3) * 4) =
            f2bf_pk(a, b);
      }
    }
  }

  // ---- acc init with bias ----
  f32x16 acc[2][2];
#pragma unroll
  for (int ct = 0; ct < 2; ++ct) {
    float bv = bias[ng * 64 + ct * 32 + mrow];
#pragma unroll
    for (int ohl = 0; ohl < 2; ++ohl)
#pragma unroll
      for (int r = 0; r < 16; ++r) acc[ohl][ct][r] = bv;
  }

  // ---- zero-VALU LDS read pointers ----
  unsigned uu = (mrow + khalf) & 7;
  const unsigned char* Pb = smem + (mg * 2 * 34 + mrow) * 128;
  const unsigned char* P[8];
#pragma unroll
  for (int j = 0; j < 8; ++j) P[j] = Pb + ((uu + j) & 7) * 16;

  __syncthreads();

  // ---- A preload step 0 (s=0: kh=kw=0, cic=0 -> j=0, offset 0) ----
  short8 aa[2][2];
#pragma unroll
  for (int ohl = 0; ohl < 2; ++ohl)
    aa[0][ohl] = *(const short8*)(P[0] + ((ohl * 34) << 7));

  // ---- K loop: 36 steps (tap,cic), fully unrolled, barrier-free ----
#pragma unroll
  for (int s = 0; s < 36; ++s) {
    if (s + 2 < 36) {
#pragma unroll
      for (int ct = 0; ct < 2; ++ct)
        bb[(s + 2) % 3][ct] = wf[(s + 2) * 256 + ct * 64 + bbase];
    }
    if (s + 1 < 36) {
      const int s1 = s + 1;
      const int kh1 = s1 / 12, kw1 = (s1 / 4) % 3, cic1 = s1 & 3;
      const int j1 = (2 * cic1 + kw1) & 7;
#pragma unroll
      for (int ohl = 0; ohl < 2; ++ohl)
        aa[s1 & 1][ohl] =
            *(const short8*)(P[j1] + ((((ohl + kh1) * 34) + kw1) << 7));
    }
#pragma unroll
    for (int ohl = 0; ohl < 2; ++ohl)
#pragma unroll
      for (int ct = 0; ct < 2; ++ct)
        acc[ohl][ct] = __builtin_amdgcn_mfma_f32_32x32x16_bf16(
            aa[s & 1][ohl], bb[s % 3][ct], acc[ohl][ct], 0, 0, 0);
  }

  // ---- epilogue ----
  // C/D: col = lane&31 (co), row = (r&3)+8*(r>>2)+4*khalf (pixel m = ow).
  __syncthreads();          // A-tile dead; reuse smem for reduction
  float* epi = (float*)smem;  // [px 256][36 words]: ng*16 + co' in words 0..31
#pragma unroll
  for (int ohl = 0; ohl < 2; ++ohl) {
#pragma unroll
    for (int r = 0; r < 16; ++r) {
      float v = fminf(acc[ohl][0][r], acc[ohl][1][r]);       // min over ct
      v = fminf(v, __shfl_xor(v, 16, 64));                   // min over co pairs
      if ((lane & 16) == 0) {
        int px = (mg * 2 + ohl) * 32 + ((r & 3) + 8 * (r >> 2) + 4 * khalf);
        epi[px * 36 + ng * 16 + (lane & 15)] = v;
      }
    }
  }
  __syncthreads();
  if (tid < 256) {
    int px = tid;
    int oh = oh0 + (px >> 5);
    const f32x4* rowp = (const f32x4*)(epi + px * 36);
    f32x4 m4 = rowp[0];
#pragma unroll
    for (int k = 1; k < 8; ++k) {
      f32x4 t = rowp[k];
      m4[0] = fminf(m4[0], t[0]); m4[1] = fminf(m4[1], t[1]);
      m4[2] = fminf(m4[2], t[2]); m4[3] = fminf(m4[3], t[3]);
    }
    float v = fminf(fminf(m4[0], m4[1]), fminf(m4[2], m4[3]));
    v = tanhf(tanhf(v));
    if (oh < OHH)
      out[(size_t)n * (OHH * OWW) + (size_t)oh * OWW + ow0 + (px & 31)] = v;
  }
}

// ---------------------------------------------------------------------------
// Fallback (only if ws too small): direct fp32 conv, 8 px per block.
// ---------------------------------------------------------------------------
__global__ __launch_bounds__(128) void fallback_kernel(
    const float* __restrict__ x, const float* __restrict__ wt,
    const float* __restrict__ bias, float* __restrict__ out) {
  __shared__ float patch[64 * 30];
  __shared__ float red[128];
  int pb   = blockIdx.x;
  int owt  = pb % 28;
  int rest = pb / 28;
  int oh   = rest % OHH;
  int n    = rest / OHH;
  int ow0  = owt * 8;
  int tid  = threadIdx.x;
  for (int i = tid; i < 1920; i += 128) {
    int wl = i % 10;
    int rr = (i / 10) % 3;
    int ci = i / 30;
    int wg = ow0 + wl;
    float v = 0.f;
    if (wg < WW) v = x[((size_t)(n * 64 + ci) * HH + (oh + rr)) * WW + wg];
    patch[i] = v;
  }
  __syncthreads();
  int co = tid;
  float a[8];
#pragma unroll
  for (int p = 0; p < 8; ++p) a[p] = bias[co];
  for (int ci = 0; ci < 64; ++ci) {
#pragma unroll
    for (int rr = 0; rr < 3; ++rr)
#pragma unroll
      for (int kw = 0; kw < 3; ++kw) {
        float wvv = wt[(size_t)co * 576 + ci * 9 + rr * 3 + kw];
        const float* pp = &patch[ci * 30 + rr * 10 + kw];
#pragma unroll
        for (int p = 0; p < 8; ++p) a[p] += pp[p] * wvv;
      }
  }
  for (int p = 0; p < 8; ++p) {
    red[tid] = a[p];
    __syncthreads();
    for (int st = 64; st > 0; st >>= 1) {
      if (tid < st) red[tid] = fminf(red[tid], red[tid + st]);
      __syncthreads();
    }
    if (tid == 0 && (ow0 + p) < OWW)
      out[(size_t)n * (OHH * OWW) + (size_t)oh * OWW + ow0 + p] = tanhf(tanhf(red[0]));
    __syncthreads();
  }
}

// ---------------------------------------------------------------------------
extern "C" void kernel_launch(void* const* d_in, const int* in_sizes, int n_in,
                              void* d_out, int out_size, void* d_ws, size_t ws_size,
                              hipStream_t stream) {
  const float* x    = (const float*)d_in[0];
  const float* wt   = (const float*)d_in[1];
  const float* bias = (const float*)d_in[2];
  float* out        = (float*)d_out;

  if (ws_size >= WS_NEED) {
    unsigned char* ws = (unsigned char*)d_ws;
    prep_w_kernel<<<36, 256, 0, stream>>>(wt, ws);
    conv_min_kernel<<<NN * 28 * 7, 512, 0, stream>>>(x, bias, ws, out);
  } else {
    fallback_kernel<<<NN * OHH * 28, 128, 0, stream>>>(x, wt, bias, out);
  }
}

// Round 4
// 401.634 us; speedup vs baseline: 1.1126x; 1.1126x over previous
//
#include <hip/hip_runtime.h>
#include <hip/hip_bf16.h>
#include <math.h>

// Problem constants
#define NN   16
#define CI   64
#define HH   224
#define WW   224
#define CO   128
#define OHH  222
#define OWW  222

// ws holds ONLY prep_w's B fragments (144 KB) -> tiny poison cost.
#define WS_NEED (36*4*64*16)   // 147456

typedef short  short8  __attribute__((ext_vector_type(8)));
typedef float  f32x16  __attribute__((ext_vector_type(16)));
typedef float  f32x4   __attribute__((ext_vector_type(4)));

__device__ static inline unsigned f2bf_pk(float a, float b) {
  __hip_bfloat162 h = __float22bfloat162_rn(make_float2(a, b));  // v_cvt_pk_bf16_f32
  return *reinterpret_cast<unsigned*>(&h);
}

// ---------------------------------------------------------------------------
// prep_w: weights [Co][Ci][3][3] fp32 -> B fragments in mfma lane order.
// frag (s, ctg): s = tap*4+cic (tap=kh*3+kw), ctg 0..3; element ((s*4+ctg)*64+lane).
// B[k][n]: n = lane&31 (co within 32-tile), k = (lane>>5)*8 + j.  (UNCHANGED)
// ---------------------------------------------------------------------------
__global__ __launch_bounds__(256) void prep_w_kernel(const float* __restrict__ wt,
                                                     unsigned char* __restrict__ ws) {
  int t    = blockIdx.x * 256 + threadIdx.x;       // 0..9215
  int lane = t & 63;
  int f    = t >> 6;                               // 0..143
  int s    = f >> 2;
  int ct   = f & 3;
  int tap  = s >> 2;
  int cic  = s & 3;
  int kh   = tap / 3, kw = tap % 3;
  int co   = ct * 32 + (lane & 31);
  int k0   = cic * 16 + (lane >> 5) * 8;
  unsigned pk[4];
#pragma unroll
  for (int j = 0; j < 4; ++j) {
    int ci0 = k0 + 2 * j;
    float a = wt[(size_t)co * 576 + (ci0    ) * 9 + kh * 3 + kw];
    float b = wt[(size_t)co * 576 + (ci0 + 1) * 9 + kh * 3 + kw];
    pk[j] = f2bf_pk(a, b);
  }
  ((uint4*)ws)[t] = make_uint4(pk[0], pk[1], pk[2], pk[3]);
}

// ---------------------------------------------------------------------------
// conv v7: v5 skeleton (clean, VGPR 56) + memory-level-parallelism fixes.
// Block 512 thr / 8 waves covers 4 oh x 32 ow x 128 co; wave = 1 oh x 32 ow
// x 64 co, acc[2] = 32 regs (v6's acc[2][2] at (512,4) spilled 157 MB).
// Changes vs v5:
//  (1) staging burst: all 12 main loads issued before any cvt/ds_write
//      (v5: 6 serial rounds, each exposing ~1.5-2k cyc of scattered-stream
//      latency); halo path re-mapped to 384 threads x 1 load (was 64 thr x
//      6 serial rounds).
//  (2) A-prefetch distance 2 via aa[3] rotation (v5 distance 1: ~64 cyc of
//      MFMA issue per step vs ~120+ cyc LDS latency -> per-step stall).
// Register audit: K-loop steady acc32+bb24+aa12+P8+misc ~86; staging peak
// ~115 < 128 budget of (512,4). Spill tripwire: WRITE_SIZE >> 3 MB.
// ---------------------------------------------------------------------------
__global__ __launch_bounds__(512, 4) void conv_min_kernel(
    const float* __restrict__ x, const float* __restrict__ bias,
    const unsigned char* __restrict__ ws, float* __restrict__ out) {
  __shared__ __align__(16) unsigned char smem[6 * 34 * 128];  // 26112 B

  int bid = blockIdx.x;
  // XCD-aware bijective swizzle: grid = 6272 = 8 * 784. Vertical neighbors
  // (bid +/- 7, sharing 2 input rows) land in the same XCD chunk.
  bid = (bid & 7) * (NN * 56 * 7 / 8) + (bid >> 3);

  int owt  = bid % 7;
  int rest = bid / 7;
  int oht  = rest % 56;
  int n    = rest / 56;
  int ow0  = (owt < 6) ? owt * 32 : 190;   // last ow tile overlaps (same values)
  int oh0  = oht * 4;                      // oh 222/223 masked at store

  int tid   = threadIdx.x;
  int wv    = tid >> 6;    // 0..7
  int lane  = tid & 63;
  int mg    = wv >> 1;     // oh row 0..3
  int ng    = wv & 1;      // co half
  int mrow  = lane & 31;
  int khalf = lane >> 5;

  // ---- B prologue (issue before staging so loads overlap) ----
  const short8* wf = (const short8*)ws;
  int bbase = ng * 128 + lane;
  short8 bb[3][2];
#pragma unroll
  for (int ct = 0; ct < 2; ++ct) bb[0][ct] = wf[0 * 256 + ct * 64 + bbase];
#pragma unroll
  for (int ct = 0; ct < 2; ++ct) bb[1][ct] = wf[1 * 256 + ct * 64 + bbase];

  // ---- in-kernel A staging: 6 rows x 34 cols x 64 ci bf16, rotated slots ----
  // slot(row,col): chunk cc (ci 8cc..8cc+7) at byte ((cc+col)&7)*16, word pp&3.
  // Burst form: issue ALL loads, then convert+write (one latency exposure).
  {
    const float* xb = x + (size_t)n * 64 * 50176;
    // main path: each thread one (col-pair, ci-pair) for all 6 rows
    int colm = (tid & 15) * 2;     // main cols 0..31 (pairs)
    int q    = tid >> 4;           // ci-pair 0..31
    int cc   = q >> 2, jw = (q & 3) * 4;
    int w0off = (((cc + colm    ) & 7) << 4) + jw;
    int w1off = (((cc + colm + 1) & 7) << 4) + jw;
    const float* xm = xb + (size_t)(q * 2) * 50176 + ow0 + colm;
    float2 A2[6], B2[6];
#pragma unroll
    for (int r = 0; r < 6; ++r) {
      int rg = oh0 + r; if (rg > 223) rg = 223;
      const float* s0 = xm + (size_t)rg * 224;
      A2[r] = *(const float2*)s0;
      B2[r] = *(const float2*)(s0 + 50176);
    }
    // halo cols 32,33: 384 threads x 1 element (ow0+33 <= 223: never OOB)
    int re   = tid >> 6;           // 0..7 (use 0..5)
    int cole = 32 + ((tid >> 5) & 1);
    int ppe  = tid & 31;
    float ea = 0.f, eb = 0.f;
    const float* xe = xb + (size_t)(ppe * 2) * 50176 + ow0 + cole;
    if (re < 6) {
      int rg = oh0 + re; if (rg > 223) rg = 223;
      ea = xe[(size_t)rg * 224];
      eb = xe[(size_t)rg * 224 + 50176];
    }
    // convert + write (compiler inserts counted vmcnt as rows drain)
#pragma unroll
    for (int r = 0; r < 6; ++r) {
      unsigned u0 = f2bf_pk(A2[r].x, B2[r].x);
      unsigned u1 = f2bf_pk(A2[r].y, B2[r].y);
      *(unsigned*)(smem + (r * 34 + colm    ) * 128 + w0off) = u0;
      *(unsigned*)(smem + (r * 34 + colm + 1) * 128 + w1off) = u1;
    }
    if (re < 6) {
      int eoff = ((((ppe >> 2) + cole) & 7) << 4) + (ppe & 3) * 4;
      *(unsigned*)(smem + (re * 34 + cole) * 128 + eoff) = f2bf_pk(ea, eb);
    }
  }

  // ---- acc init with bias ----
  f32x16 acc[2];
#pragma unroll
  for (int ct = 0; ct < 2; ++ct) {
    float bv = bias[ng * 64 + ct * 32 + mrow];
#pragma unroll
    for (int r = 0; r < 16; ++r) acc[ct][r] = bv;
  }

  // ---- zero-VALU LDS read pointers ----
  unsigned uu = (mrow + khalf) & 7;
  const unsigned char* Pb = smem + (mg * 34 + mrow) * 128;
  const unsigned char* P[8];
#pragma unroll
  for (int j = 0; j < 8; ++j) P[j] = Pb + ((uu + j) & 7) * 16;

  __syncthreads();

  // ---- A preload steps 0,1 (distance-2 pipeline) ----
  // s=0: kh=kw=0,cic=0 -> j=0, off 0.  s=1: kh=kw=0,cic=1 -> j=2, off 0.
  short8 aa[3];
  aa[0] = *(const short8*)(P[0]);
  aa[1] = *(const short8*)(P[2]);

  // ---- K loop: 36 steps (tap,cic), fully unrolled, barrier-free ----
#pragma unroll
  for (int s = 0; s < 36; ++s) {
    if (s + 2 < 36) {
#pragma unroll
      for (int ct = 0; ct < 2; ++ct)
        bb[(s + 2) % 3][ct] = wf[(s + 2) * 256 + ct * 64 + bbase];
      const int s2 = s + 2;
      const int kh2 = s2 / 12, kw2 = (s2 / 4) % 3, cic2 = s2 & 3;
      const int j2 = (2 * cic2 + kw2) & 7;
      aa[s2 % 3] = *(const short8*)(P[j2] + ((kh2 * 34 + kw2) << 7));
    }
#pragma unroll
    for (int ct = 0; ct < 2; ++ct)
      acc[ct] = __builtin_amdgcn_mfma_f32_32x32x16_bf16(
          aa[s % 3], bb[s % 3][ct], acc[ct], 0, 0, 0);
  }

  // ---- epilogue ----
  // C/D: col = lane&31 (co), row = (r&3)+8*(r>>2)+4*khalf (pixel m = ow).
  __syncthreads();          // A-tile dead; reuse smem for reduction
  float* epi = (float*)smem;  // [px 128][36 words]: ng*16 + co' in words 0..31
#pragma unroll
  for (int r = 0; r < 16; ++r) {
    float v = fminf(acc[0][r], acc[1][r]);                 // min over ct
    v = fminf(v, __shfl_xor(v, 16, 64));                   // min over co pairs
    if ((lane & 16) == 0) {
      int px = mg * 32 + ((r & 3) + 8 * (r >> 2) + 4 * khalf);
      epi[px * 36 + ng * 16 + (lane & 15)] = v;
    }
  }
  __syncthreads();
  if (tid < 128) {
    int px = tid;
    int oh = oh0 + (px >> 5);
    const f32x4* rowp = (const f32x4*)(epi + px * 36);
    f32x4 m4 = rowp[0];
#pragma unroll
    for (int k = 1; k < 8; ++k) {
      f32x4 t = rowp[k];
      m4[0] = fminf(m4[0], t[0]); m4[1] = fminf(m4[1], t[1]);
      m4[2] = fminf(m4[2], t[2]); m4[3] = fminf(m4[3], t[3]);
    }
    float v = fminf(fminf(m4[0], m4[1]), fminf(m4[2], m4[3]));
    v = tanhf(tanhf(v));
    if (oh < OHH)
      out[(size_t)n * (OHH * OWW) + (size_t)oh * OWW + ow0 + (px & 31)] = v;
  }
}

// ---------------------------------------------------------------------------
// Fallback (only if ws too small): direct fp32 conv, 8 px per block.
// ---------------------------------------------------------------------------
__global__ __launch_bounds__(128) void fallback_kernel(
    const float* __restrict__ x, const float* __restrict__ wt,
    const float* __restrict__ bias, float* __restrict__ out) {
  __shared__ float patch[64 * 30];
  __shared__ float red[128];
  int pb   = blockIdx.x;
  int owt  = pb % 28;
  int rest = pb / 28;
  int oh   = rest % OHH;
  int n    = rest / OHH;
  int ow0  = owt * 8;
  int tid  = threadIdx.x;
  for (int i = tid; i < 1920; i += 128) {
    int wl = i % 10;
    int rr = (i / 10) % 3;
    int ci = i / 30;
    int wg = ow0 + wl;
    float v = 0.f;
    if (wg < WW) v = x[((size_t)(n * 64 + ci) * HH + (oh + rr)) * WW + wg];
    patch[i] = v;
  }
  __syncthreads();
  int co = tid;
  float a[8];
#pragma unroll
  for (int p = 0; p < 8; ++p) a[p] = bias[co];
  for (int ci = 0; ci < 64; ++ci) {
#pragma unroll
    for (int rr = 0; rr < 3; ++rr)
#pragma unroll
      for (int kw = 0; kw < 3; ++kw) {
        float wvv = wt[(size_t)co * 576 + ci * 9 + rr * 3 + kw];
        const float* pp = &patch[ci * 30 + rr * 10 + kw];
#pragma unroll
        for (int p = 0; p < 8; ++p) a[p] += pp[p] * wvv;
      }
  }
  for (int p = 0; p < 8; ++p) {
    red[tid] = a[p];
    __syncthreads();
    for (int st = 64; st > 0; st >>= 1) {
      if (tid < st) red[tid] = fminf(red[tid], red[tid + st]);
      __syncthreads();
    }
    if (tid == 0 && (ow0 + p) < OWW)
      out[(size_t)n * (OHH * OWW) + (size_t)oh * OWW + ow0 + p] = tanhf(tanhf(red[0]));
    __syncthreads();
  }
}

// ---------------------------------------------------------------------------
extern "C" void kernel_launch(void* const* d_in, const int* in_sizes, int n_in,
                              void* d_out, int out_size, void* d_ws, size_t ws_size,
                              hipStream_t stream) {
  const float* x    = (const float*)d_in[0];
  const float* wt   = (const float*)d_in[1];
  const float* bias = (const float*)d_in[2];
  float* out        = (float*)d_out;

  if (ws_size >= WS_NEED) {
    unsigned char* ws = (unsigned char*)d_ws;
    prep_w_kernel<<<36, 256, 0, stream>>>(wt, ws);
    conv_min_kernel<<<NN * 56 * 7, 512, 0, stream>>>(x, bias, ws, out);
  } else {
    fallback_kernel<<<NN * OHH * 28, 128, 0, stream>>>(x, wt, bias, out);
  }
}

// Round 5
// 372.893 us; speedup vs baseline: 1.1984x; 1.0771x over previous
//
#include <hip/hip_runtime.h>
#include <hip/hip_bf16.h>
#include <math.h>

// Problem constants
#define NN   16
#define CI   64
#define HH   224
#define WW   224
#define CO   128
#define OHH  222
#define OWW  222

// ws holds ONLY prep_w's B fragments (144 KB) -> tiny poison cost.
#define WS_NEED (36*4*64*16)   // 147456

#define A_BYTES (6*34*128)     // 26112
#define BCHUNK  24576          // 6 K-steps * 4 frags * 64 lanes * 16 B

typedef short  short8  __attribute__((ext_vector_type(8)));
typedef float  f32x16  __attribute__((ext_vector_type(16)));
typedef float  f32x4   __attribute__((ext_vector_type(4)));

__device__ static inline unsigned f2bf_pk(float a, float b) {
  __hip_bfloat162 h = __float22bfloat162_rn(make_float2(a, b));  // v_cvt_pk_bf16_f32
  return *reinterpret_cast<unsigned*>(&h);
}

// ---------------------------------------------------------------------------
// prep_w: weights [Co][Ci][3][3] fp32 -> B fragments in mfma lane order.
// frag (s, ctg): s = tap*4+cic (tap=kh*3+kw), ctg 0..3; element ((s*4+ctg)*64+lane).
// B[k][n]: n = lane&31 (co within 32-tile), k = (lane>>5)*8 + j.  (UNCHANGED)
// ---------------------------------------------------------------------------
__global__ __launch_bounds__(256) void prep_w_kernel(const float* __restrict__ wt,
                                                     unsigned char* __restrict__ ws) {
  int t    = blockIdx.x * 256 + threadIdx.x;       // 0..9215
  int lane = t & 63;
  int f    = t >> 6;                               // 0..143
  int s    = f >> 2;
  int ct   = f & 3;
  int tap  = s >> 2;
  int cic  = s & 3;
  int kh   = tap / 3, kw = tap % 3;
  int co   = ct * 32 + (lane & 31);
  int k0   = cic * 16 + (lane >> 5) * 8;
  unsigned pk[4];
#pragma unroll
  for (int j = 0; j < 4; ++j) {
    int ci0 = k0 + 2 * j;
    float a = wt[(size_t)co * 576 + (ci0    ) * 9 + kh * 3 + kw];
    float b = wt[(size_t)co * 576 + (ci0 + 1) * 9 + kh * 3 + kw];
    pk[j] = f2bf_pk(a, b);
  }
  ((uint4*)ws)[t] = make_uint4(pk[0], pk[1], pk[2], pk[3]);
}

// ---------------------------------------------------------------------------
// conv v8: v7 + B through LDS (chunked double-buffer).
// v7 counters: MfmaUtil 23.7%, nothing saturated; B = 2 L2 loads/step/wave =
// 3.7 GB through L2 (~17 TB/s, 50% of peak) with prefetch distance 2 covering
// ~32 cyc of a contended ~400+ cyc L2 hit -> every step exposes L2 latency.
// Fix: ws is linear in (step, frag, lane), so stage B in 6 chunks x 24 KB via
// regs (3 dwordx4 + 3 ds_write_b128/thread, T14 issue-early/write-late),
// double-buffered; K-loop reads B via ds_read_b128 (conflict-free, ~120 cyc,
// distance-2 prefetch within chunk). B L2 traffic /4; per-step wait -> LDS.
// LDS 26112(A) + 2*24576(B) = 75264 -> still 2 blocks/CU.
// Regs: acc32+bb24+aa12+P8+breg12+addr ~ 106 < 128 budget of (512,4).
// Spill tripwire: WRITE_SIZE >> 3 MB.
// ---------------------------------------------------------------------------
__global__ __launch_bounds__(512, 4) void conv_min_kernel(
    const float* __restrict__ x, const float* __restrict__ bias,
    const unsigned char* __restrict__ ws, float* __restrict__ out) {
  __shared__ __align__(16) unsigned char smem[A_BYTES + 2 * BCHUNK];  // 75264 B

  int bid = blockIdx.x;
  // XCD-aware bijective swizzle: grid = 6272 = 8 * 784. Vertical neighbors
  // (bid +/- 7, sharing 2 input rows) land in the same XCD chunk.
  bid = (bid & 7) * (NN * 56 * 7 / 8) + (bid >> 3);

  int owt  = bid % 7;
  int rest = bid / 7;
  int oht  = rest % 56;
  int n    = rest / 56;
  int ow0  = (owt < 6) ? owt * 32 : 190;   // last ow tile overlaps (same values)
  int oh0  = oht * 4;                      // oh 222/223 masked at store

  int tid   = threadIdx.x;
  int wv    = tid >> 6;    // 0..7
  int lane  = tid & 63;
  int mg    = wv >> 1;     // oh row 0..3
  int ng    = wv & 1;      // co half
  int mrow  = lane & 31;
  int khalf = lane >> 5;

  // ---- staging: A burst (v7) + B chunk 0, all loads issued before writes ----
  {
    const float* xb = x + (size_t)n * 64 * 50176;
    // main path: each thread one (col-pair, ci-pair) for all 6 rows
    int colm = (tid & 15) * 2;     // main cols 0..31 (pairs)
    int q    = tid >> 4;           // ci-pair 0..31
    int cc   = q >> 2, jw = (q & 3) * 4;
    int w0off = (((cc + colm    ) & 7) << 4) + jw;
    int w1off = (((cc + colm + 1) & 7) << 4) + jw;
    const float* xm = xb + (size_t)(q * 2) * 50176 + ow0 + colm;
    float2 A2[6], B2[6];
#pragma unroll
    for (int r = 0; r < 6; ++r) {
      int rg = oh0 + r; if (rg > 223) rg = 223;
      const float* s0 = xm + (size_t)rg * 224;
      A2[r] = *(const float2*)s0;
      B2[r] = *(const float2*)(s0 + 50176);
    }
    // B chunk 0 loads (ws chunk bytes are fully contiguous)
    uint4 b0[3];
#pragma unroll
    for (int r = 0; r < 3; ++r)
      b0[r] = *(const uint4*)(ws + r * 8192 + (size_t)tid * 16);
    // halo cols 32,33: 384 threads x 1 element (ow0+33 <= 223: never OOB)
    int re   = tid >> 6;           // 0..7 (use 0..5)
    int cole = 32 + ((tid >> 5) & 1);
    int ppe  = tid & 31;
    float ea = 0.f, eb = 0.f;
    const float* xe = xb + (size_t)(ppe * 2) * 50176 + ow0 + cole;
    if (re < 6) {
      int rg = oh0 + re; if (rg > 223) rg = 223;
      ea = xe[(size_t)rg * 224];
      eb = xe[(size_t)rg * 224 + 50176];
    }
    // convert + write (compiler inserts counted vmcnt as loads drain)
#pragma unroll
    for (int r = 0; r < 6; ++r) {
      unsigned u0 = f2bf_pk(A2[r].x, B2[r].x);
      unsigned u1 = f2bf_pk(A2[r].y, B2[r].y);
      *(unsigned*)(smem + (r * 34 + colm    ) * 128 + w0off) = u0;
      *(unsigned*)(smem + (r * 34 + colm + 1) * 128 + w1off) = u1;
    }
#pragma unroll
    for (int r = 0; r < 3; ++r)
      *(uint4*)(smem + A_BYTES + r * 8192 + (size_t)tid * 16) = b0[r];
    if (re < 6) {
      int eoff = ((((ppe >> 2) + cole) & 7) << 4) + (ppe & 3) * 4;
      *(unsigned*)(smem + (re * 34 + cole) * 128 + eoff) = f2bf_pk(ea, eb);
    }
  }

  // ---- acc init with bias ----
  f32x16 acc[2];
#pragma unroll
  for (int ct = 0; ct < 2; ++ct) {
    float bv = bias[ng * 64 + ct * 32 + mrow];
#pragma unroll
    for (int r = 0; r < 16; ++r) acc[ct][r] = bv;
  }

  // ---- zero-VALU LDS read pointers (A path, rotated slots) ----
  unsigned uu = (mrow + khalf) & 7;
  const unsigned char* Pb = smem + (mg * 34 + mrow) * 128;
  const unsigned char* P[8];
#pragma unroll
  for (int j = 0; j < 8; ++j) P[j] = Pb + ((uu + j) & 7) * 16;

  // B read base (wave-constant except ct/step/buf compile-time offsets)
  const unsigned char* Bw = smem + A_BYTES + ng * 2048 + lane * 16;

  __syncthreads();

  // ---- A preload steps 0,1 (distance-2 pipeline) ----
  // s=0: kh=kw=0,cic=0 -> j=0, off 0.  s=1: kh=kw=0,cic=1 -> j=2, off 0.
  short8 aa[3];
  aa[0] = *(const short8*)(P[0]);
  aa[1] = *(const short8*)(P[2]);

  // ---- B preload steps 0,1 of chunk 0 from LDS ----
  short8 bb[3][2];
#pragma unroll
  for (int ct = 0; ct < 2; ++ct) {
    bb[0][ct] = *(const short8*)(Bw + 0 * 4096 + ct * 1024);
    bb[1][ct] = *(const short8*)(Bw + 1 * 4096 + ct * 1024);
  }

  // ---- K loop: 6 chunks x 6 steps, fully unrolled ----
  uint4 breg[3];
#pragma unroll
  for (int ch = 0; ch < 6; ++ch) {
    const int p = ch & 1;
    if (ch + 1 < 6) {     // issue next-chunk B loads early (hide L2 under MFMA)
#pragma unroll
      for (int r = 0; r < 3; ++r)
        breg[r] = *(const uint4*)(ws + (ch + 1) * BCHUNK + r * 8192 + (size_t)tid * 16);
    }
#pragma unroll
    for (int si = 0; si < 6; ++si) {
      const int s = ch * 6 + si;
      if (si + 2 < 6) {   // B prefetch distance 2 (within chunk)
#pragma unroll
        for (int ct = 0; ct < 2; ++ct)
          bb[(si + 2) % 3][ct] =
              *(const short8*)(Bw + p * BCHUNK + (si + 2) * 4096 + ct * 1024);
      }
      if (s + 2 < 36) {   // A prefetch distance 2 (tile static, crosses chunks)
        const int s2 = s + 2;
        const int kh2 = s2 / 12, kw2 = (s2 / 4) % 3, cic2 = s2 & 3;
        const int j2 = (2 * cic2 + kw2) & 7;
        aa[s2 % 3] = *(const short8*)(P[j2] + ((kh2 * 34 + kw2) << 7));
      }
#pragma unroll
      for (int ct = 0; ct < 2; ++ct)
        acc[ct] = __builtin_amdgcn_mfma_f32_32x32x16_bf16(
            aa[s % 3], bb[si % 3][ct], acc[ct], 0, 0, 0);
    }
    if (ch + 1 < 6) {     // write next chunk into other buffer, then sync
      unsigned char* dst = smem + A_BYTES + (p ^ 1) * BCHUNK + (size_t)tid * 16;
#pragma unroll
      for (int r = 0; r < 3; ++r)
        *(uint4*)(dst + r * 8192) = breg[r];
      __syncthreads();
      // preload bb for first two steps of next chunk
#pragma unroll
      for (int ct = 0; ct < 2; ++ct) {
        bb[0][ct] = *(const short8*)(Bw + (p ^ 1) * BCHUNK + 0 * 4096 + ct * 1024);
        bb[1][ct] = *(const short8*)(Bw + (p ^ 1) * BCHUNK + 1 * 4096 + ct * 1024);
      }
    }
  }

  // ---- epilogue ----
  // C/D: col = lane&31 (co), row = (r&3)+8*(r>>2)+4*khalf (pixel m = ow).
  __syncthreads();          // A-tile dead; reuse smem for reduction
  float* epi = (float*)smem;  // [px 128][36 words]: ng*16 + co' in words 0..31
#pragma unroll
  for (int r = 0; r < 16; ++r) {
    float v = fminf(acc[0][r], acc[1][r]);                 // min over ct
    v = fminf(v, __shfl_xor(v, 16, 64));                   // min over co pairs
    if ((lane & 16) == 0) {
      int px = mg * 32 + ((r & 3) + 8 * (r >> 2) + 4 * khalf);
      epi[px * 36 + ng * 16 + (lane & 15)] = v;
    }
  }
  __syncthreads();
  if (tid < 128) {
    int px = tid;
    int oh = oh0 + (px >> 5);
    const f32x4* rowp = (const f32x4*)(epi + px * 36);
    f32x4 m4 = rowp[0];
#pragma unroll
    for (int k = 1; k < 8; ++k) {
      f32x4 t = rowp[k];
      m4[0] = fminf(m4[0], t[0]); m4[1] = fminf(m4[1], t[1]);
      m4[2] = fminf(m4[2], t[2]); m4[3] = fminf(m4[3], t[3]);
    }
    float v = fminf(fminf(m4[0], m4[1]), fminf(m4[2], m4[3]));
    v = tanhf(tanhf(v));
    if (oh < OHH)
      out[(size_t)n * (OHH * OWW) + (size_t)oh * OWW + ow0 + (px & 31)] = v;
  }
}

// ---------------------------------------------------------------------------
// Fallback (only if ws too small): direct fp32 conv, 8 px per block.
// ---------------------------------------------------------------------------
__global__ __launch_bounds__(128) void fallback_kernel(
    const float* __restrict__ x, const float* __restrict__ wt,
    const float* __restrict__ bias, float* __restrict__ out) {
  __shared__ float patch[64 * 30];
  __shared__ float red[128];
  int pb   = blockIdx.x;
  int owt  = pb % 28;
  int rest = pb / 28;
  int oh   = rest % OHH;
  int n    = rest / OHH;
  int ow0  = owt * 8;
  int tid  = threadIdx.x;
  for (int i = tid; i < 1920; i += 128) {
    int wl = i % 10;
    int rr = (i / 10) % 3;
    int ci = i / 30;
    int wg = ow0 + wl;
    float v = 0.f;
    if (wg < WW) v = x[((size_t)(n * 64 + ci) * HH + (oh + rr)) * WW + wg];
    patch[i] = v;
  }
  __syncthreads();
  int co = tid;
  float a[8];
#pragma unroll
  for (int p = 0; p < 8; ++p) a[p] = bias[co];
  for (int ci = 0; ci < 64; ++ci) {
#pragma unroll
    for (int rr = 0; rr < 3; ++rr)
#pragma unroll
      for (int kw = 0; kw < 3; ++kw) {
        float wvv = wt[(size_t)co * 576 + ci * 9 + rr * 3 + kw];
        const float* pp = &patch[ci * 30 + rr * 10 + kw];
#pragma unroll
        for (int p = 0; p < 8; ++p) a[p] += pp[p] * wvv;
      }
  }
  for (int p = 0; p < 8; ++p) {
    red[tid] = a[p];
    __syncthreads();
    for (int st = 64; st > 0; st >>= 1) {
      if (tid < st) red[tid] = fminf(red[tid], red[tid + st]);
      __syncthreads();
    }
    if (tid == 0 && (ow0 + p) < OWW)
      out[(size_t)n * (OHH * OWW) + (size_t)oh * OWW + ow0 + p] = tanhf(tanhf(red[0]));
    __syncthreads();
  }
}

// ---------------------------------------------------------------------------
extern "C" void kernel_launch(void* const* d_in, const int* in_sizes, int n_in,
                              void* d_out, int out_size, void* d_ws, size_t ws_size,
                              hipStream_t stream) {
  const float* x    = (const float*)d_in[0];
  const float* wt   = (const float*)d_in[1];
  const float* bias = (const float*)d_in[2];
  float* out        = (float*)d_out;

  if (ws_size >= WS_NEED) {
    unsigned char* ws = (unsigned char*)d_ws;
    prep_w_kernel<<<36, 256, 0, stream>>>(wt, ws);
    conv_min_kernel<<<NN * 56 * 7, 512, 0, stream>>>(x, bias, ws, out);
  } else {
    fallback_kernel<<<NN * OHH * 28, 128, 0, stream>>>(x, wt, bias, out);
  }
}

// Round 7
// 365.684 us; speedup vs baseline: 1.2220x; 1.0197x over previous
//
#include <hip/hip_runtime.h>
#include <hip/hip_bf16.h>
#include <math.h>

// Problem constants
#define NN   16
#define CI   64
#define HH   224
#define WW   224
#define CO   128
#define OHH  222
#define OWW  222

// ws holds ONLY prep_w's B fragments (144 KB) -> tiny poison cost.
#define WS_NEED (36*4*64*16)   // 147456

#define A_BYTES (10*34*128)    // 43520
#define BCHUNK  16384          // 4 K-steps * 4 frags * 64 lanes * 16 B
#define NCHUNK  9              // 36 steps / 4

typedef short  short8  __attribute__((ext_vector_type(8)));
typedef float  f32x16  __attribute__((ext_vector_type(16)));
typedef float  f32x4   __attribute__((ext_vector_type(4)));

__device__ static inline unsigned f2bf_pk(float a, float b) {
  __hip_bfloat162 h = __float22bfloat162_rn(make_float2(a, b));  // v_cvt_pk_bf16_f32
  return *reinterpret_cast<unsigned*>(&h);
}

// async 16B global->LDS (no VGPR round-trip). Dest must be linear in lane order:
// here both sides are base + tid*16, exactly the wave-uniform+lane*16 pattern.
__device__ static inline void gload_lds16(const void* g, void* l) {
  __builtin_amdgcn_global_load_lds(
      (const __attribute__((address_space(1))) unsigned int*)g,
      (__attribute__((address_space(3))) unsigned int*)l, 16, 0, 0);
}

// ---------------------------------------------------------------------------
// prep_w: weights [Co][Ci][3][3] fp32 -> B fragments in mfma lane order.
// frag (s, ctg): s = tap*4+cic (tap=kh*3+kw), ctg 0..3; element ((s*4+ctg)*64+lane).
// B[k][n]: n = lane&31 (co within 32-tile), k = (lane>>5)*8 + j.  (UNCHANGED)
// ---------------------------------------------------------------------------
__global__ __launch_bounds__(256) void prep_w_kernel(const float* __restrict__ wt,
                                                     unsigned char* __restrict__ ws) {
  int t    = blockIdx.x * 256 + threadIdx.x;       // 0..9215
  int lane = t & 63;
  int f    = t >> 6;                               // 0..143
  int s    = f >> 2;
  int ct   = f & 3;
  int tap  = s >> 2;
  int cic  = s & 3;
  int kh   = tap / 3, kw = tap % 3;
  int co   = ct * 32 + (lane & 31);
  int k0   = cic * 16 + (lane >> 5) * 8;
  unsigned pk[4];
#pragma unroll
  for (int j = 0; j < 4; ++j) {
    int ci0 = k0 + 2 * j;
    float a = wt[(size_t)co * 576 + (ci0    ) * 9 + kh * 3 + kw];
    float b = wt[(size_t)co * 576 + (ci0 + 1) * 9 + kh * 3 + kw];
    pk[j] = f2bf_pk(a, b);
  }
  ((uint4*)ws)[t] = make_uint4(pk[0], pk[1], pk[2], pk[3]);
}

// ---------------------------------------------------------------------------
// conv v9 (resubmit; R6 bench died in infra before dispatch — no counters,
// no compile error). Rationale vs v8 (184 us, MfmaUtil 28.5%):
// v8 was LDS-read-BW-bound: 5.55 GB of K-loop ds_read in 184 us = 30 TB/s,
// ~255k of the 441k cyc/CU wall; no other pipe >28%. Block 512 thr / 8 waves
// = 8 oh x 32 ow x 128 co; wave = 2 oh x 64 co: per step 4 MFMA from 2A+2B
// reads (1.0 KB/MFMA vs v8's 1.5). B staged via global_load_lds (both sides
// linear, wave-uniform+lane*16): zero staging VGPRs/ds_writes -- the headroom
// that makes acc[2][2]=64 fit the (512,4) 128-reg budget where v6 spilled
// (steady ~116 regs). B dbuf = 2 x 4-step chunks (16 KB); LDS 43520 + 32768
// = 76288 -> 2 blk/CU. Halo amortization improves (10 input rows / 8 output
// rows vs 6/4). Spill tripwire: WRITE_SIZE >> 3 MB.
// Race audit: chunk-boundary __syncthreads drains vmcnt(0) -> in-flight
// gload_lds complete before reads of buffer p^1; all reads of the old chunk
// precede its re-targeting (reads happen before that same barrier).
// ---------------------------------------------------------------------------
__global__ __launch_bounds__(512, 4) void conv_min_kernel(
    const float* __restrict__ x, const float* __restrict__ bias,
    const unsigned char* __restrict__ ws, float* __restrict__ out) {
  __shared__ __align__(16) unsigned char smem[A_BYTES + 2 * BCHUNK];  // 76288 B

  int bid = blockIdx.x;
  // XCD-aware bijective swizzle: grid = 3136 = 8 * 392. Vertical neighbors
  // (bid +/- 7, sharing 2 input rows) land in the same XCD chunk.
  bid = (bid & 7) * (NN * 28 * 7 / 8) + (bid >> 3);

  int owt  = bid % 7;
  int rest = bid / 7;
  int oht  = rest % 28;
  int n    = rest / 28;
  int ow0  = (owt < 6) ? owt * 32 : 190;   // last ow tile overlaps (same values)
  int oh0  = oht * 8;                      // oh 222/223 masked at store

  int tid   = threadIdx.x;
  int wv    = tid >> 6;    // 0..7
  int lane  = tid & 63;
  int mg    = wv >> 1;     // oh row-pair 0..3 (rows 2mg, 2mg+1)
  int ng    = wv & 1;      // co half
  int mrow  = lane & 31;
  int khalf = lane >> 5;

  // ---- staging: B chunk 0 via async gload_lds, A burst via regs ----
  {
    // B chunk 0 (async; drained by the staging __syncthreads)
#pragma unroll
    for (int r = 0; r < 2; ++r)
      gload_lds16(ws + r * 8192 + (size_t)tid * 16,
                  smem + A_BYTES + r * 8192 + (size_t)tid * 16);

    const float* xb = x + (size_t)n * 64 * 50176;
    // main path: each thread one (col-pair, ci-pair) for all 10 rows
    int colm = (tid & 15) * 2;     // main cols 0..31 (pairs)
    int q    = tid >> 4;           // ci-pair 0..31
    int cc   = q >> 2, jw = (q & 3) * 4;
    int w0off = (((cc + colm    ) & 7) << 4) + jw;
    int w1off = (((cc + colm + 1) & 7) << 4) + jw;
    const float* xm = xb + (size_t)(q * 2) * 50176 + ow0 + colm;
    float2 A2[10], B2[10];
#pragma unroll
    for (int r = 0; r < 10; ++r) {
      int rg = oh0 + r; if (rg > 223) rg = 223;
      const float* s0 = xm + (size_t)rg * 224;
      A2[r] = *(const float2*)s0;
      B2[r] = *(const float2*)(s0 + 50176);
    }
    // halo cols 32,33 (ow0+33 <= 223: never OOB): rows 0..7 by all threads,
    // rows 8,9 by tid<128.
    int cole = 32 + ((tid >> 5) & 1);
    int ppe  = tid & 31;
    int re   = tid >> 6;           // 0..7
    const float* xe = xb + (size_t)(ppe * 2) * 50176 + ow0 + cole;
    int rg1 = oh0 + re; if (rg1 > 223) rg1 = 223;
    float ea = xe[(size_t)rg1 * 224];
    float eb = xe[(size_t)rg1 * 224 + 50176];
    float ea2 = 0.f, eb2 = 0.f;
    int re2 = 8 + (tid >> 6);      // valid for tid<128 -> rows 8,9
    if (tid < 128) {
      int rg2 = oh0 + re2; if (rg2 > 223) rg2 = 223;
      ea2 = xe[(size_t)rg2 * 224];
      eb2 = xe[(size_t)rg2 * 224 + 50176];
    }
    // convert + write (compiler inserts counted vmcnt as loads drain)
#pragma unroll
    for (int r = 0; r < 10; ++r) {
      unsigned u0 = f2bf_pk(A2[r].x, B2[r].x);
      unsigned u1 = f2bf_pk(A2[r].y, B2[r].y);
      *(unsigned*)(smem + (r * 34 + colm    ) * 128 + w0off) = u0;
      *(unsigned*)(smem + (r * 34 + colm + 1) * 128 + w1off) = u1;
    }
    {
      int eoff = ((((ppe >> 2) + cole) & 7) << 4) + (ppe & 3) * 4;
      *(unsigned*)(smem + (re * 34 + cole) * 128 + eoff) = f2bf_pk(ea, eb);
      if (tid < 128)
        *(unsigned*)(smem + (re2 * 34 + cole) * 128 + eoff) = f2bf_pk(ea2, eb2);
    }
  }

  // ---- acc init with bias ----
  f32x16 acc[2][2];
#pragma unroll
  for (int ct = 0; ct < 2; ++ct) {
    float bv = bias[ng * 64 + ct * 32 + mrow];
#pragma unroll
    for (int ohl = 0; ohl < 2; ++ohl)
#pragma unroll
      for (int r = 0; r < 16; ++r) acc[ohl][ct][r] = bv;
  }

  // ---- zero-VALU LDS read pointers (A path, rotated slots) ----
  unsigned uu = (mrow + khalf) & 7;
  const unsigned char* Pb = smem + (mg * 2 * 34 + mrow) * 128;
  const unsigned char* P[8];
#pragma unroll
  for (int j = 0; j < 8; ++j) P[j] = Pb + ((uu + j) & 7) * 16;

  // B read base (per-lane; buf/step/ct are compile-time offsets)
  const unsigned char* Bw = smem + A_BYTES + ng * 2048 + lane * 16;

  __syncthreads();   // drains A ds_writes AND chunk-0 gload_lds

  // ---- preload step 0: A (s=0: kh=kw=cic=0 -> j=0, off 0) and B (si=0) ----
  short8 aa[2][2], bb[2][2];
#pragma unroll
  for (int ohl = 0; ohl < 2; ++ohl)
    aa[0][ohl] = *(const short8*)(P[0] + ((ohl * 34) << 7));
#pragma unroll
  for (int ct = 0; ct < 2; ++ct)
    bb[0][ct] = *(const short8*)(Bw + 0 * 4096 + ct * 1024);

  // ---- K loop: 9 chunks x 4 steps, fully unrolled ----
#pragma unroll
  for (int ch = 0; ch < NCHUNK; ++ch) {
    const int p = ch & 1;
    if (ch + 1 < NCHUNK) {   // async-issue next chunk into other buffer
#pragma unroll
      for (int r = 0; r < 2; ++r)
        gload_lds16(ws + (ch + 1) * BCHUNK + r * 8192 + (size_t)tid * 16,
                    smem + A_BYTES + (p ^ 1) * BCHUNK + r * 8192 + (size_t)tid * 16);
    }
#pragma unroll
    for (int si = 0; si < 4; ++si) {
      const int s = ch * 4 + si;
      if (si < 3) {          // B prefetch distance 1 (within chunk)
#pragma unroll
        for (int ct = 0; ct < 2; ++ct)
          bb[(si + 1) & 1][ct] =
              *(const short8*)(Bw + p * BCHUNK + (si + 1) * 4096 + ct * 1024);
      }
      if (s + 1 < 36) {      // A prefetch distance 1 (tile static)
        const int s1 = s + 1;
        const int kh1 = s1 / 12, kw1 = (s1 / 4) % 3, cic1 = s1 & 3;
        const int j1 = (2 * cic1 + kw1) & 7;
#pragma unroll
        for (int ohl = 0; ohl < 2; ++ohl)
          aa[s1 & 1][ohl] =
              *(const short8*)(P[j1] + ((((ohl + kh1) * 34) + kw1) << 7));
      }
#pragma unroll
      for (int ohl = 0; ohl < 2; ++ohl)
#pragma unroll
        for (int ct = 0; ct < 2; ++ct)
          acc[ohl][ct] = __builtin_amdgcn_mfma_f32_32x32x16_bf16(
              aa[s & 1][ohl], bb[si & 1][ct], acc[ohl][ct], 0, 0, 0);
    }
    if (ch + 1 < NCHUNK) {   // next buffer ready: sync, preload its step 0
      __syncthreads();
#pragma unroll
      for (int ct = 0; ct < 2; ++ct)
        bb[0][ct] = *(const short8*)(Bw + (p ^ 1) * BCHUNK + 0 * 4096 + ct * 1024);
    }
  }

  // ---- epilogue ----
  // C/D: col = lane&31 (co), row = (r&3)+8*(r>>2)+4*khalf (pixel m = ow).
  __syncthreads();          // A-tile dead; reuse smem for reduction
  float* epi = (float*)smem;  // [px 256][36 words]: ng*16 + co' in words 0..31
#pragma unroll
  for (int ohl = 0; ohl < 2; ++ohl) {
#pragma unroll
    for (int r = 0; r < 16; ++r) {
      float v = fminf(acc[ohl][0][r], acc[ohl][1][r]);       // min over ct
      v = fminf(v, __shfl_xor(v, 16, 64));                   // min over co pairs
      if ((lane & 16) == 0) {
        int px = (mg * 2 + ohl) * 32 + ((r & 3) + 8 * (r >> 2) + 4 * khalf);
        epi[px * 36 + ng * 16 + (lane & 15)] = v;
      }
    }
  }
  __syncthreads();
  if (tid < 256) {
    int px = tid;
    int oh = oh0 + (px >> 5);
    const f32x4* rowp = (const f32x4*)(epi + px * 36);
    f32x4 m4 = rowp[0];
#pragma unroll
    for (int k = 1; k < 8; ++k) {
      f32x4 t = rowp[k];
      m4[0] = fminf(m4[0], t[0]); m4[1] = fminf(m4[1], t[1]);
      m4[2] = fminf(m4[2], t[2]); m4[3] = fminf(m4[3], t[3]);
    }
    float v = fminf(fminf(m4[0], m4[1]), fminf(m4[2], m4[3]));
    v = tanhf(tanhf(v));
    if (oh < OHH)
      out[(size_t)n * (OHH * OWW) + (size_t)oh * OWW + ow0 + (px & 31)] = v;
  }
}

// ---------------------------------------------------------------------------
// Fallback (only if ws too small): direct fp32 conv, 8 px per block.
// ---------------------------------------------------------------------------
__global__ __launch_bounds__(128) void fallback_kernel(
    const float* __restrict__ x, const float* __restrict__ wt,
    const float* __restrict__ bias, float* __restrict__ out) {
  __shared__ float patch[64 * 30];
  __shared__ float red[128];
  int pb   = blockIdx.x;
  int owt  = pb % 28;
  int rest = pb / 28;
  int oh   = rest % OHH;
  int n    = rest / OHH;
  int ow0  = owt * 8;
  int tid  = threadIdx.x;
  for (int i = tid; i < 1920; i += 128) {
    int wl = i % 10;
    int rr = (i / 10) % 3;
    int ci = i / 30;
    int wg = ow0 + wl;
    float v = 0.f;
    if (wg < WW) v = x[((size_t)(n * 64 + ci) * HH + (oh + rr)) * WW + wg];
    patch[i] = v;
  }
  __syncthreads();
  int co = tid;
  float a[8];
#pragma unroll
  for (int p = 0; p < 8; ++p) a[p] = bias[co];
  for (int ci = 0; ci < 64; ++ci) {
#pragma unroll
    for (int rr = 0; rr < 3; ++rr)
#pragma unroll
      for (int kw = 0; kw < 3; ++kw) {
        float wvv = wt[(size_t)co * 576 + ci * 9 + rr * 3 + kw];
        const float* pp = &patch[ci * 30 + rr * 10 + kw];
#pragma unroll
        for (int p = 0; p < 8; ++p) a[p] += pp[p] * wvv;
      }
  }
  for (int p = 0; p < 8; ++p) {
    red[tid] = a[p];
    __syncthreads();
    for (int st = 64; st > 0; st >>= 1) {
      if (tid < st) red[tid] = fminf(red[tid], red[tid + st]);
      __syncthreads();
    }
    if (tid == 0 && (ow0 + p) < OWW)
      out[(size_t)n * (OHH * OWW) + (size_t)oh * OWW + ow0 + p] = tanhf(tanhf(red[0]));
    __syncthreads();
  }
}

// ---------------------------------------------------------------------------
extern "C" void kernel_launch(void* const* d_in, const int* in_sizes, int n_in,
                              void* d_out, int out_size, void* d_ws, size_t ws_size,
                              hipStream_t stream) {
  const float* x    = (const float*)d_in[0];
  const float* wt   = (const float*)d_in[1];
  const float* bias = (const float*)d_in[2];
  float* out        = (float*)d_out;

  if (ws_size >= WS_NEED) {
    unsigned char* ws = (unsigned char*)d_ws;
    prep_w_kernel<<<36, 256, 0, stream>>>(wt, ws);
    conv_min_kernel<<<NN * 28 * 7, 512, 0, stream>>>(x, bias, ws, out);
  } else {
    fallback_kernel<<<NN * OHH * 28, 128, 0, stream>>>(x, wt, bias, out);
  }
}